// Round 1
// baseline (334.122 us; speedup 1.0000x reference)
//
#include <hip/hip_runtime.h>

#define N_    50000
#define E_    320000
#define R_    16
#define B_    8
#define IN_   256
#define OUT_  256
#define EPR_  (E_ / R_)      // 20000 edges per relation
#define MBLK_ 157            // ceil(EPR_/128)
#define NBLK_ 391            // ceil(N_/128)

typedef float  f32x16 __attribute__((ext_vector_type(16)));
typedef __bf16 bf16x8 __attribute__((ext_vector_type(8)));

static __device__ __forceinline__ short f2bf(float f) {
  unsigned u = __float_as_uint(f);
  u = (u + 0x7FFFu + ((u >> 16) & 1u)) >> 16;   // RNE
  return (short)u;
}

// ---------------------------------------------------------------------------
// prep: w_relT[r][o][i] = sum_b w_comp[r,b]*weight[b,i,o]  (bf16, transposed)
//       loopT[o][i] = loop_weight[i][o] (bf16), feat -> bf16, zero node_acc
// ---------------------------------------------------------------------------
__global__ void prep_kernel(const float* __restrict__ feat, const float* __restrict__ weight,
                            const float* __restrict__ w_comp, const float* __restrict__ loop_w,
                            short* __restrict__ w_relT, short* __restrict__ loopT,
                            short* __restrict__ feat_bf, float* __restrict__ node_acc) {
  int gid = blockIdx.x * blockDim.x + threadIdx.x;
  int gsz = gridDim.x * blockDim.x;
  for (int idx = gid; idx < R_ * OUT_ * IN_; idx += gsz) {
    int r = idx >> 16, i = (idx >> 8) & 255, o = idx & 255;  // o fastest: coalesced weight reads
    float s = 0.f;
#pragma unroll
    for (int b = 0; b < B_; ++b)
      s += w_comp[r * B_ + b] * weight[(b * IN_ + i) * OUT_ + o];
    w_relT[(r * OUT_ + o) * IN_ + i] = f2bf(s);
  }
  for (int idx = gid; idx < OUT_ * IN_; idx += gsz) {
    int i = idx >> 8, o = idx & 255;
    loopT[o * IN_ + i] = f2bf(loop_w[i * OUT_ + o]);
  }
  for (int idx = gid; idx < (N_ * IN_) / 4; idx += gsz) {
    float4 v = ((const float4*)feat)[idx];
    short4 s4;
    s4.x = f2bf(v.x); s4.y = f2bf(v.y); s4.z = f2bf(v.z); s4.w = f2bf(v.w);
    ((short4*)feat_bf)[idx] = s4;
  }
  for (int idx = gid; idx < (N_ * OUT_) / 4; idx += gsz)
    ((float4*)node_acc)[idx] = make_float4(0.f, 0.f, 0.f, 0.f);
}

// ---------------------------------------------------------------------------
// edge: per relation r, msg = (feat[src] @ w_rel[r]) * norm, atomic scatter to dst
// tile: BM=128 edges x BN=128 out, BK=64 staged in LDS. 4 waves, wave = 32 rows.
// mfma_f32_32x32x16_bf16: A lane: row=l&31, k=(l>>5)*8+j (16B contiguous)
//                         B lane: col=l&31, k=(l>>5)*8+j
//                         C lane: col=l&31, row=(reg&3)+8*(reg>>2)+4*(l>>5)
// ---------------------------------------------------------------------------
__launch_bounds__(256)
__global__ void edge_kernel(const short* __restrict__ feat_bf, const short* __restrict__ w_relT,
                            const float* __restrict__ norm, const int* __restrict__ src_idx,
                            const int* __restrict__ dst_idx, float* __restrict__ node_acc) {
  __shared__ short lds_b[128 * 64];  // B^T slice [col 0..127][k 0..63], 16KB, chunk-swizzled
  int bid  = blockIdx.x;
  int r    = bid / (MBLK_ * 2);
  int rem  = bid - r * (MBLK_ * 2);
  int mblk = rem >> 1, nhalf = rem & 1;
  int e0   = r * EPR_ + mblk * 128;
  int rows = EPR_ - mblk * 128; if (rows > 128) rows = 128;

  int tid = threadIdx.x;
  int lane = tid & 63, wave = tid >> 6;
  int lm = lane & 31, hi = lane >> 5;
  int wr = wave << 5;

  int erow = wr + lm;
  int eg   = e0 + (erow < rows ? erow : 0);      // clamped: garbage rows never stored
  int src  = src_idx[eg];
  const bf16x8* __restrict__ arow = (const bf16x8*)(feat_bf + src * IN_);
  const short*  __restrict__ wb   = w_relT + (r * OUT_ + nhalf * 128) * IN_;

  f32x16 acc[4];
#pragma unroll
  for (int g = 0; g < 4; ++g)
#pragma unroll
    for (int t = 0; t < 16; ++t) acc[g][t] = 0.f;

  int scol = tid >> 1, sh = tid & 1;             // staging: thread -> (col, k-half)
  const bf16x8* __restrict__ gsrc0 = (const bf16x8*)(wb + scol * IN_ + sh * 32);

  for (int stage = 0; stage < 4; ++stage) {
    // ---- stage B^T[128][64] -> LDS (swizzle 16B chunk index by col&7)
#pragma unroll
    for (int c8 = 0; c8 < 4; ++c8) {
      int q = sh * 4 + c8;
      bf16x8 v = gsrc0[stage * 8 + c8];
      *(bf16x8*)(&lds_b[scol * 64 + ((q ^ (scol & 7)) << 3)]) = v;
    }
    // ---- prefetch A fragments for this stage (gathered, 16B each)
    bf16x8 af[4];
#pragma unroll
    for (int s = 0; s < 4; ++s) af[s] = arow[stage * 8 + s * 2 + hi];
    __syncthreads();
#pragma unroll
    for (int s = 0; s < 4; ++s) {
      int q = s * 2 + hi;
#pragma unroll
      for (int g = 0; g < 4; ++g) {
        int col = (g << 5) + lm;
        bf16x8 bfr = *(const bf16x8*)(&lds_b[col * 64 + ((q ^ (col & 7)) << 3)]);
        acc[g] = __builtin_amdgcn_mfma_f32_32x32x16_bf16(af[s], bfr, acc[g], 0, 0, 0);
      }
    }
    __syncthreads();
  }

  // ---- epilogue: * norm, atomic scatter to node_acc[dst]
  float nr[16]; int db[16];
#pragma unroll
  for (int t = 0; t < 16; ++t) {
    int row = (t & 3) + ((t >> 2) << 3) + (hi << 2);
    int er  = wr + row;
    int ee  = e0 + (er < rows ? er : 0);
    float nv = norm[ee];
    nr[t] = (er < rows) ? nv : 0.f;
    db[t] = dst_idx[ee] * OUT_;
  }
#pragma unroll
  for (int g = 0; g < 4; ++g) {
    int col = nhalf * 128 + (g << 5) + lm;
#pragma unroll
    for (int t = 0; t < 16; ++t) {
      if (nr[t] != 0.f)
        unsafeAtomicAdd(&node_acc[db[t] + col], acc[g][t] * nr[t]);
    }
  }
}

// ---------------------------------------------------------------------------
// selfloop: out = relu(node_acc + h_bias + feat @ loop_weight), in place on d_out
// ---------------------------------------------------------------------------
__launch_bounds__(256)
__global__ void selfloop_kernel(const short* __restrict__ feat_bf, const short* __restrict__ loopT,
                                const float* __restrict__ h_bias, float* __restrict__ inout) {
  __shared__ short lds_b[128 * 64];
  int bid = blockIdx.x;
  int mblk = bid >> 1, nhalf = bid & 1;
  int n0 = mblk << 7;
  int rows = N_ - n0; if (rows > 128) rows = 128;

  int tid = threadIdx.x;
  int lane = tid & 63, wave = tid >> 6;
  int lm = lane & 31, hi = lane >> 5;
  int wr = wave << 5;

  int nrow = wr + lm;
  int ng = n0 + (nrow < rows ? nrow : 0);
  const bf16x8* __restrict__ arow = (const bf16x8*)(feat_bf + ng * IN_);
  const short*  __restrict__ wb   = loopT + nhalf * 128 * IN_;

  f32x16 acc[4];
#pragma unroll
  for (int g = 0; g < 4; ++g)
#pragma unroll
    for (int t = 0; t < 16; ++t) acc[g][t] = 0.f;

  int scol = tid >> 1, sh = tid & 1;
  const bf16x8* __restrict__ gsrc0 = (const bf16x8*)(wb + scol * IN_ + sh * 32);

  for (int stage = 0; stage < 4; ++stage) {
#pragma unroll
    for (int c8 = 0; c8 < 4; ++c8) {
      int q = sh * 4 + c8;
      bf16x8 v = gsrc0[stage * 8 + c8];
      *(bf16x8*)(&lds_b[scol * 64 + ((q ^ (scol & 7)) << 3)]) = v;
    }
    bf16x8 af[4];
#pragma unroll
    for (int s = 0; s < 4; ++s) af[s] = arow[stage * 8 + s * 2 + hi];
    __syncthreads();
#pragma unroll
    for (int s = 0; s < 4; ++s) {
      int q = s * 2 + hi;
#pragma unroll
      for (int g = 0; g < 4; ++g) {
        int col = (g << 5) + lm;
        bf16x8 bfr = *(const bf16x8*)(&lds_b[col * 64 + ((q ^ (col & 7)) << 3)]);
        acc[g] = __builtin_amdgcn_mfma_f32_32x32x16_bf16(af[s], bfr, acc[g], 0, 0, 0);
      }
    }
    __syncthreads();
  }

#pragma unroll
  for (int g = 0; g < 4; ++g) {
    int col = nhalf * 128 + (g << 5) + lm;
    float hb = h_bias[col];
#pragma unroll
    for (int t = 0; t < 16; ++t) {
      int row = (t & 3) + ((t >> 2) << 3) + (hi << 2);
      int nn = wr + row;
      if (nn < rows) {
        int off = (n0 + nn) * OUT_ + col;
        float x = inout[off] + acc[g][t] + hb;
        inout[off] = x > 0.f ? x : 0.f;
      }
    }
  }
}

// ---------------------------------------------------------------------------
extern "C" void kernel_launch(void* const* d_in, const int* in_sizes, int n_in,
                              void* d_out, int out_size, void* d_ws, size_t ws_size,
                              hipStream_t stream) {
  const float* feat    = (const float*)d_in[0];
  const float* weight  = (const float*)d_in[1];
  const float* w_comp  = (const float*)d_in[2];
  const float* loop_w  = (const float*)d_in[3];
  const float* h_bias  = (const float*)d_in[4];
  const float* norm    = (const float*)d_in[5];
  const int*   src_idx = (const int*)d_in[6];
  const int*   dst_idx = (const int*)d_in[7];
  float* out = (float*)d_out;

  short* w_relT  = (short*)d_ws;                       // R*OUT*IN   = 2 MB
  short* loopT   = w_relT + R_ * OUT_ * IN_;           // OUT*IN     = 128 KB
  short* feat_bf = loopT + OUT_ * IN_;                 // N*IN bf16  = 25.6 MB

  prep_kernel<<<1024, 256, 0, stream>>>(feat, weight, w_comp, loop_w,
                                        w_relT, loopT, feat_bf, out);
  edge_kernel<<<MBLK_ * 2 * R_, 256, 0, stream>>>(feat_bf, w_relT, norm,
                                                  src_idx, dst_idx, out);
  selfloop_kernel<<<NBLK_ * 2, 256, 0, stream>>>(feat_bf, loopT, h_bias, out);
}